// Round 3
// baseline (284.615 us; speedup 1.0000x reference)
//
#include <hip/hip_runtime.h>

// MeanPooling: segment mean over sorted int segment ids.
//   N = 33554432 float32 values, NUM_SEGMENTS = 100000, index sorted ascending.
// Strategy: index is sorted -> segment s is the contiguous slice
//   [lower_bound(s), lower_bound(s+1)). Kernel 1 computes the 100001 boundaries
//   by binary search (touches ~10-20MB effective; top tree levels cache-resident,
//   full index L3-resident). Kernel 2 assigns one 64-lane wave per segment,
//   streams x coalesced, shuffle-reduces, writes mean. Avoids reading the
//   128MB index array element-wise entirely: HBM floor ~= x's 128MB.
// Predicted: ~10us (k1, latency-bound) + ~25us (k2, HBM-bound, FETCH~130MB).

#define NSEG 100000

__global__ __launch_bounds__(256) void bounds_kernel(
    const int* __restrict__ index, int n, int* __restrict__ seg_start) {
    int s = blockIdx.x * blockDim.x + threadIdx.x;
    if (s > NSEG) return;
    // lower_bound: first i with index[i] >= s. For s == NSEG this yields n
    // (all values < NSEG), giving the terminating boundary.
    int lo = 0, hi = n;
    while (lo < hi) {
        int mid = (lo + hi) >> 1;          // n < 2^31, no overflow
        if (index[mid] < s) lo = mid + 1; else hi = mid;
    }
    seg_start[s] = lo;
}

__global__ __launch_bounds__(256) void segsum_kernel(
    const float* __restrict__ x, const int* __restrict__ seg_start,
    float* __restrict__ out) {
    int wave_id = (int)((blockIdx.x * blockDim.x + threadIdx.x) >> 6);
    int lane = threadIdx.x & 63;
    if (wave_id >= NSEG) return;

    int beg = seg_start[wave_id];
    int end = seg_start[wave_id + 1];

    float sum = 0.0f;
    for (int i = beg + lane; i < end; i += 64) sum += x[i];

    // wave-64 butterfly reduce
    #pragma unroll
    for (int off = 32; off > 0; off >>= 1) sum += __shfl_down(sum, off, 64);

    if (lane == 0) {
        int cnt = end - beg;
        out[wave_id] = sum / (float)(cnt > 0 ? cnt : 1);
    }
}

extern "C" void kernel_launch(void* const* d_in, const int* in_sizes, int n_in,
                              void* d_out, int out_size, void* d_ws, size_t ws_size,
                              hipStream_t stream) {
    const float* x   = (const float*)d_in[0];
    const int*   idx = (const int*)d_in[1];
    float*       out = (float*)d_out;
    int n = in_sizes[0];

    int* seg_start = (int*)d_ws;  // NSEG+1 ints = 400004 B of scratch

    // Kernel 1: boundaries via binary search, one thread per segment edge.
    {
        int threads = 256;
        int blocks = (NSEG + 1 + threads - 1) / threads;
        bounds_kernel<<<blocks, threads, 0, stream>>>(idx, n, seg_start);
    }

    // Kernel 2: one wave per segment, coalesced sum + mean.
    {
        int threads = 256;                       // 4 waves/block
        int waves_per_block = threads / 64;
        int blocks = (NSEG + waves_per_block - 1) / waves_per_block;
        segsum_kernel<<<blocks, threads, 0, stream>>>(x, seg_start, out);
    }
}